// Round 1
// baseline (524.334 us; speedup 1.0000x reference)
//
#include <hip/hip_runtime.h>

#define F_IN 128
#define HID 16
#define C_OUT 8

// deg[d] += 1 for each edge
__global__ void deg_kernel(const int* __restrict__ dst, float* __restrict__ deg, int E) {
    int i = blockIdx.x * blockDim.x + threadIdx.x;
    if (i < E) atomicAdd(&deg[dst[i]], 1.0f);
}

// dis = rsqrt(deg + 1)   (+1 = self-loop)
__global__ void dis_kernel(float* __restrict__ deg, int N) {
    int i = blockIdx.x * blockDim.x + threadIdx.x;
    if (i < N) deg[i] = rsqrtf(deg[i] + 1.0f);
}

// hs1[n,:] = (x[n,:] @ W1) * dis[n]
__global__ void h1_kernel(const float* __restrict__ x, const float* __restrict__ W1,
                          const float* __restrict__ dis, float* __restrict__ hs1, int N) {
    __shared__ float w[F_IN * HID];
    for (int t = threadIdx.x; t < F_IN * HID; t += blockDim.x) w[t] = W1[t];
    __syncthreads();
    int row = blockIdx.x * blockDim.x + threadIdx.x;
    if (row >= N) return;
    float acc[HID];
#pragma unroll
    for (int j = 0; j < HID; ++j) acc[j] = 0.f;
    const float4* xr = reinterpret_cast<const float4*>(x + (size_t)row * F_IN);
#pragma unroll 4
    for (int k4 = 0; k4 < F_IN / 4; ++k4) {
        float4 v = xr[k4];
        int k = k4 * 4;
#pragma unroll
        for (int j = 0; j < HID; ++j) {
            acc[j] += v.x * w[(k + 0) * HID + j] + v.y * w[(k + 1) * HID + j]
                    + v.z * w[(k + 2) * HID + j] + v.w * w[(k + 3) * HID + j];
        }
    }
    float d = dis[row];
    float4* o = reinterpret_cast<float4*>(hs1 + (size_t)row * HID);
#pragma unroll
    for (int q = 0; q < HID / 4; ++q) {
        float4 r;
        r.x = acc[q * 4 + 0] * d;
        r.y = acc[q * 4 + 1] * d;
        r.z = acc[q * 4 + 2] * d;
        r.w = acc[q * 4 + 3] * d;
        o[q] = r;
    }
}

// thread t handles edge e = t/16, component j = t%16
__global__ void scatter16_kernel(const int* __restrict__ src, const int* __restrict__ dst,
                                 const float* __restrict__ hs, float* __restrict__ acc, int total) {
    int t = blockIdx.x * blockDim.x + threadIdx.x;
    if (t >= total) return;
    int e = t >> 4;
    int j = t & 15;
    int s = src[e];
    int d = dst[e];
    atomicAdd(&acc[(size_t)d * HID + j], hs[(size_t)s * HID + j]);
}

__global__ void scatter8_kernel(const int* __restrict__ src, const int* __restrict__ dst,
                                const float* __restrict__ hs, float* __restrict__ acc, int total) {
    int t = blockIdx.x * blockDim.x + threadIdx.x;
    if (t >= total) return;
    int e = t >> 3;
    int j = t & 7;
    int s = src[e];
    int d = dst[e];
    atomicAdd(&acc[(size_t)d * C_OUT + j], hs[(size_t)s * C_OUT + j]);
}

// r = relu(dis*(acc1+hs1)+b1);  hs2 = dis * (r @ W2)
__global__ void fin1_kernel(const float* __restrict__ acc1, const float* __restrict__ hs1,
                            const float* __restrict__ dis, const float* __restrict__ b1,
                            const float* __restrict__ W2, float* __restrict__ hs2, int N) {
    __shared__ float w[HID * C_OUT];
    __shared__ float bb[HID];
    if (threadIdx.x < HID * C_OUT) w[threadIdx.x] = W2[threadIdx.x];
    if (threadIdx.x < HID) bb[threadIdx.x] = b1[threadIdx.x];
    __syncthreads();
    int n = blockIdx.x * blockDim.x + threadIdx.x;
    if (n >= N) return;
    float d = dis[n];
    const float4* a4 = reinterpret_cast<const float4*>(acc1 + (size_t)n * HID);
    const float4* h4 = reinterpret_cast<const float4*>(hs1 + (size_t)n * HID);
    float r[HID];
#pragma unroll
    for (int q = 0; q < HID / 4; ++q) {
        float4 av = a4[q];
        float4 hv = h4[q];
        float v0 = d * (av.x + hv.x) + bb[q * 4 + 0];
        float v1 = d * (av.y + hv.y) + bb[q * 4 + 1];
        float v2 = d * (av.z + hv.z) + bb[q * 4 + 2];
        float v3 = d * (av.w + hv.w) + bb[q * 4 + 3];
        r[q * 4 + 0] = v0 > 0.f ? v0 : 0.f;
        r[q * 4 + 1] = v1 > 0.f ? v1 : 0.f;
        r[q * 4 + 2] = v2 > 0.f ? v2 : 0.f;
        r[q * 4 + 3] = v3 > 0.f ? v3 : 0.f;
    }
    float4* o = reinterpret_cast<float4*>(hs2 + (size_t)n * C_OUT);
#pragma unroll
    for (int q = 0; q < C_OUT / 4; ++q) {
        float4 rv;
        float a0 = 0.f, a1 = 0.f, a2 = 0.f, a3 = 0.f;
#pragma unroll
        for (int j = 0; j < HID; ++j) {
            float rj = r[j];
            a0 += rj * w[j * C_OUT + q * 4 + 0];
            a1 += rj * w[j * C_OUT + q * 4 + 1];
            a2 += rj * w[j * C_OUT + q * 4 + 2];
            a3 += rj * w[j * C_OUT + q * 4 + 3];
        }
        rv.x = a0 * d; rv.y = a1 * d; rv.z = a2 * d; rv.w = a3 * d;
        o[q] = rv;
    }
}

// out[n,c] = dis[n]*(out[n,c] + hs2[n,c]) + b2[c]   (in place on d_out)
__global__ void fin2_kernel(float* __restrict__ out, const float* __restrict__ hs2,
                            const float* __restrict__ dis, const float* __restrict__ b2, int total) {
    int i = blockIdx.x * blockDim.x + threadIdx.x;
    if (i >= total) return;
    int n = i >> 3;
    int c = i & 7;
    out[i] = dis[n] * (out[i] + hs2[i]) + b2[c];
}

extern "C" void kernel_launch(void* const* d_in, const int* in_sizes, int n_in,
                              void* d_out, int out_size, void* d_ws, size_t ws_size,
                              hipStream_t stream) {
    const float* x  = (const float*)d_in[0];
    const int*   ei = (const int*)d_in[1];
    const float* W1 = (const float*)d_in[2];
    const float* b1 = (const float*)d_in[3];
    const float* W2 = (const float*)d_in[4];
    const float* b2 = (const float*)d_in[5];
    float* out = (float*)d_out;

    int N = in_sizes[0] / F_IN;
    int E = in_sizes[1] / 2;
    const int* src = ei;
    const int* dst = ei + E;

    float* ws   = (float*)d_ws;
    float* deg  = ws;                      // N floats (becomes dis)
    float* acc1 = ws + N;                  // 16N floats
    float* hs1  = ws + (size_t)17 * N;     // 16N floats
    float* hs2  = ws + (size_t)33 * N;     // 8N floats

    hipMemsetAsync(ws, 0, (size_t)17 * N * sizeof(float), stream);
    hipMemsetAsync(out, 0, (size_t)N * C_OUT * sizeof(float), stream);

    const int B = 256;
    deg_kernel<<<(E + B - 1) / B, B, 0, stream>>>(dst, deg, E);
    dis_kernel<<<(N + B - 1) / B, B, 0, stream>>>(deg, N);
    h1_kernel<<<(N + B - 1) / B, B, 0, stream>>>(x, W1, deg, hs1, N);

    int t1 = E * HID;  // 51.2M
    scatter16_kernel<<<(t1 + B - 1) / B, B, 0, stream>>>(src, dst, hs1, acc1, t1);

    fin1_kernel<<<(N + B - 1) / B, B, 0, stream>>>(acc1, hs1, deg, b1, W2, hs2, N);

    int t2 = E * C_OUT;  // 25.6M
    scatter8_kernel<<<(t2 + B - 1) / B, B, 0, stream>>>(src, dst, hs2, out, t2);

    int t3 = N * C_OUT;
    fin2_kernel<<<(t3 + B - 1) / B, B, 0, stream>>>(out, hs2, deg, b2, t3);
}